// Round 1
// baseline (608.104 us; speedup 1.0000x reference)
//
#include <hip/hip_runtime.h>

#define NHEADS 4
#define HIDC 64
#define NEG_SLOPE 0.2f
#define EPS_LN 1e-5f

// ---------------- CSR build ----------------
__global__ __launch_bounds__(256) void k_init_deg(int* __restrict__ deg, int n) {
    int i = blockIdx.x * 256 + threadIdx.x;
    if (i < n) deg[i] = 1;  // self-loop
}

__global__ __launch_bounds__(256) void k_count(const int* __restrict__ dst, int* __restrict__ deg, int e) {
    int i = blockIdx.x * 256 + threadIdx.x;
    if (i < e) atomicAdd(&deg[dst[i]], 1);
}

__global__ __launch_bounds__(256) void k_scan1(const int* __restrict__ deg, int* __restrict__ rs,
                                               int* __restrict__ bsum, int n) {
    __shared__ int tmp[256];
    int tx = threadIdx.x;
    int i = blockIdx.x * 256 + tx;
    int v = (i < n) ? deg[i] : 0;
    tmp[tx] = v;
    __syncthreads();
    for (int off = 1; off < 256; off <<= 1) {
        int t = (tx >= off) ? tmp[tx - off] : 0;
        __syncthreads();
        tmp[tx] += t;
        __syncthreads();
    }
    if (i < n) rs[i] = tmp[tx] - v;           // exclusive, pre-block-offset
    if (tx == 255) bsum[blockIdx.x] = tmp[255];
}

__global__ __launch_bounds__(256) void k_scan2(int* __restrict__ bsum, int nb) {
    __shared__ int tmp[256];
    int tx = threadIdx.x;
    int v = (tx < nb) ? bsum[tx] : 0;
    tmp[tx] = v;
    __syncthreads();
    for (int off = 1; off < 256; off <<= 1) {
        int t = (tx >= off) ? tmp[tx - off] : 0;
        __syncthreads();
        tmp[tx] += t;
        __syncthreads();
    }
    if (tx < nb) bsum[tx] = tmp[tx] - v;      // exclusive block offsets
}

__global__ __launch_bounds__(256) void k_scan3(int* __restrict__ rs, int* __restrict__ cur,
                                               const int* __restrict__ bsum, int n, int total) {
    int i = blockIdx.x * 256 + threadIdx.x;
    if (i < n) {
        int r = rs[i] + bsum[blockIdx.x];
        rs[i] = r;
        cur[i] = r;
    }
    if (i == 0) rs[n] = total;
}

__global__ __launch_bounds__(256) void k_scatter(const int* __restrict__ src, const int* __restrict__ dst,
                                                 int* __restrict__ cur, int* __restrict__ col, int e, int n) {
    int i = blockIdx.x * 256 + threadIdx.x;
    if (i < e + n) {
        int s, d;
        if (i < e) { s = src[i]; d = dst[i]; }
        else       { s = i - e;  d = i - e;  }   // self-loops appended (order within a dst is irrelevant)
        int p = atomicAdd(&cur[d], 1);
        col[p] = s;
    }
}

// ---------------- fp32 tiled GEMM: C[M,N] = A[M,K] @ B[K,N] (+bias) ----------------
// 64x64 tile, 4x4 per thread, K staged in chunks of 16. K must be multiple of 16, N multiple of 64.
__global__ __launch_bounds__(256) void k_gemm(const float* __restrict__ A, const float* __restrict__ B,
                                              const float* __restrict__ bias, float* __restrict__ C,
                                              int M, int N, int K) {
    __shared__ float As[16][68];   // [k][m], row stride 68 (mult of 4 -> float4-aligned, breaks 2^n bank stride)
    __shared__ float Bs[16][68];   // [k][n]
    int tid = threadIdx.x;
    int m0 = blockIdx.x * 64, n0 = blockIdx.y * 64;
    int ty = tid >> 4, tx = tid & 15;
    int lm = tid >> 2;            // 0..63 A row
    int lk4 = (tid & 3) * 4;      // A k-offset
    int lkb = tid >> 4;           // 0..15 B row
    int lnb = (tid & 15) * 4;     // B col
    float acc[4][4] = {};
    for (int k0 = 0; k0 < K; k0 += 16) {
        float4 a4;
        int am = m0 + lm;
        if (am < M) a4 = *(const float4*)&A[(size_t)am * K + k0 + lk4];
        else        a4 = make_float4(0.f, 0.f, 0.f, 0.f);
        As[lk4 + 0][lm] = a4.x; As[lk4 + 1][lm] = a4.y;
        As[lk4 + 2][lm] = a4.z; As[lk4 + 3][lm] = a4.w;
        *(float4*)&Bs[lkb][lnb] = *(const float4*)&B[(size_t)(k0 + lkb) * N + n0 + lnb];
        __syncthreads();
#pragma unroll
        for (int k = 0; k < 16; k++) {
            float4 a = *(const float4*)&As[k][ty * 4];
            float4 b = *(const float4*)&Bs[k][tx * 4];
            acc[0][0] += a.x * b.x; acc[0][1] += a.x * b.y; acc[0][2] += a.x * b.z; acc[0][3] += a.x * b.w;
            acc[1][0] += a.y * b.x; acc[1][1] += a.y * b.y; acc[1][2] += a.y * b.z; acc[1][3] += a.y * b.w;
            acc[2][0] += a.z * b.x; acc[2][1] += a.z * b.y; acc[2][2] += a.z * b.z; acc[2][3] += a.z * b.w;
            acc[3][0] += a.w * b.x; acc[3][1] += a.w * b.y; acc[3][2] += a.w * b.z; acc[3][3] += a.w * b.w;
        }
        __syncthreads();
    }
#pragma unroll
    for (int i = 0; i < 4; i++) {
        int m = m0 + ty * 4 + i;
        if (m < M) {
            int nbase = n0 + tx * 4;
            float4 r;
            r.x = acc[i][0]; r.y = acc[i][1]; r.z = acc[i][2]; r.w = acc[i][3];
            if (bias) {
                r.x += bias[nbase + 0]; r.y += bias[nbase + 1];
                r.z += bias[nbase + 2]; r.w += bias[nbase + 3];
            }
            *(float4*)&C[(size_t)m * N + nbase] = r;
        }
    }
}

// ---------------- attention coefficients: es/ed [N,4] ----------------
__global__ __launch_bounds__(256) void k_attn_coef(const float* __restrict__ h, const float* __restrict__ asrc,
                                                   const float* __restrict__ adst, float* __restrict__ es,
                                                   float* __restrict__ ed, int n) {
    int node = blockIdx.x * 4 + (threadIdx.x >> 6);
    int lane = threadIdx.x & 63;
    if (node >= n) return;
    const float* hp = h + (size_t)node * 256;
#pragma unroll
    for (int hh = 0; hh < NHEADS; hh++) {
        float v = hp[hh * 64 + lane];
        float s = v * asrc[hh * 64 + lane];
        float d = v * adst[hh * 64 + lane];
        for (int off = 32; off; off >>= 1) {
            s += __shfl_xor(s, off, 64);
            d += __shfl_xor(d, off, 64);
        }
        if (lane == 0) { es[node * 4 + hh] = s; ed[node * 4 + hh] = d; }
    }
}

// ---------------- fused GAT aggregate + head-mean + bias + LN + ReLU ----------------
// one wave per destination node; lane = channel, 4 heads per lane (strided coalesced loads)
__global__ __launch_bounds__(256) void k_gat_aggregate(const float* __restrict__ h, const float* __restrict__ es,
                                                       const float* __restrict__ ed, const int* __restrict__ rs,
                                                       const int* __restrict__ col, const float* __restrict__ b,
                                                       const float* __restrict__ g, const float* __restrict__ be,
                                                       float* __restrict__ out, int n) {
    int node = blockIdx.x * 4 + (threadIdx.x >> 6);
    int lane = threadIdx.x & 63;
    if (node >= n) return;
    float4 edv = *(const float4*)&ed[node * 4];
    float acc0 = 0.f, acc1 = 0.f, acc2 = 0.f, acc3 = 0.f;
    float den0 = 0.f, den1 = 0.f, den2 = 0.f, den3 = 0.f;
    int i0 = rs[node], i1 = rs[node + 1];
    for (int i = i0; i < i1; i++) {
        int s = col[i];
        float4 esv = *(const float4*)&es[s * 4];
        float e0 = esv.x + edv.x, e1 = esv.y + edv.y, e2 = esv.z + edv.z, e3 = esv.w + edv.w;
        e0 = e0 > 0.f ? e0 : NEG_SLOPE * e0;
        e1 = e1 > 0.f ? e1 : NEG_SLOPE * e1;
        e2 = e2 > 0.f ? e2 : NEG_SLOPE * e2;
        e3 = e3 > 0.f ? e3 : NEG_SLOPE * e3;
        // no max-subtraction: |e| is O(5), exp is safe; softmax is identical
        float w0 = __expf(e0), w1 = __expf(e1), w2 = __expf(e2), w3 = __expf(e3);
        const float* hp = h + (size_t)s * 256 + lane;
        acc0 += w0 * hp[0];
        acc1 += w1 * hp[64];
        acc2 += w2 * hp[128];
        acc3 += w3 * hp[192];
        den0 += w0; den1 += w1; den2 += w2; den3 += w3;
    }
    float val = 0.25f * (acc0 / den0 + acc1 / den1 + acc2 / den2 + acc3 / den3) + b[lane];
    // LayerNorm over 64 channels (= the wave), biased variance like jnp.var
    float s = val, q = val * val;
    for (int off = 32; off; off >>= 1) {
        s += __shfl_xor(s, off, 64);
        q += __shfl_xor(q, off, 64);
    }
    float mean = s * (1.f / 64.f);
    float var = q * (1.f / 64.f) - mean * mean;
    float y = (val - mean) * rsqrtf(var + EPS_LN) * g[lane] + be[lane];
    out[(size_t)node * 64 + lane] = fmaxf(y, 0.f);
}

// ---------------- launch ----------------
extern "C" void kernel_launch(void* const* d_in, const int* in_sizes, int n_in,
                              void* d_out, int out_size, void* d_ws, size_t ws_size,
                              hipStream_t stream) {
    const float* x     = (const float*)d_in[0];
    const int*   eidx  = (const int*)d_in[1];
    const float* W1    = (const float*)d_in[2];
    const float* asrc1 = (const float*)d_in[3];
    const float* adst1 = (const float*)d_in[4];
    const float* b1    = (const float*)d_in[5];
    const float* g1    = (const float*)d_in[6];
    const float* be1   = (const float*)d_in[7];
    const float* W2    = (const float*)d_in[8];
    const float* asrc2 = (const float*)d_in[9];
    const float* adst2 = (const float*)d_in[10];
    const float* b2    = (const float*)d_in[11];
    const float* g2    = (const float*)d_in[12];
    const float* be2   = (const float*)d_in[13];
    const float* Wo    = (const float*)d_in[14];
    const float* bo    = (const float*)d_in[15];

    const int N = in_sizes[0] / 128;
    const int E = in_sizes[1] / 2;
    const int* srcp = eidx;
    const int* dstp = eidx + E;

    // workspace layout
    float* wf = (float*)d_ws;
    float* h_big   = wf;                                   // [N,256] (h1, then h3)
    float* h_small = h_big + (size_t)N * 256;              // [N,64]  (h2, then h4)
    float* es      = h_small + (size_t)N * 64;             // [N,4]
    float* ed      = es + (size_t)N * 4;                   // [N,4]
    int* deg       = (int*)(ed + (size_t)N * 4);           // [N]
    int* rowstart  = deg + N;                              // [N+1]
    int* cursor    = rowstart + (N + 1);                   // [N]
    int* colarr    = cursor + N;                           // [E+N]
    int* bsum      = colarr + (size_t)(E + N);             // [<=256]

    const int nb = (N + 255) / 256;
    const int nwb = (N + 3) / 4;           // node-wave blocks (4 waves/block)
    const int mtiles = (N + 63) / 64;

    // CSR build (re-done each launch: ws is re-poisoned)
    k_init_deg<<<nb, 256, 0, stream>>>(deg, N);
    k_count<<<(E + 255) / 256, 256, 0, stream>>>(dstp, deg, E);
    k_scan1<<<nb, 256, 0, stream>>>(deg, rowstart, bsum, N);
    k_scan2<<<1, 256, 0, stream>>>(bsum, nb);
    k_scan3<<<nb, 256, 0, stream>>>(rowstart, cursor, bsum, N, E + N);
    k_scatter<<<(E + N + 255) / 256, 256, 0, stream>>>(srcp, dstp, cursor, colarr, E, N);

    // layer 1
    k_gemm<<<dim3(mtiles, 4), 256, 0, stream>>>(x, W1, nullptr, h_big, N, 256, 128);
    k_attn_coef<<<nwb, 256, 0, stream>>>(h_big, asrc1, adst1, es, ed, N);
    k_gat_aggregate<<<nwb, 256, 0, stream>>>(h_big, es, ed, rowstart, colarr, b1, g1, be1, h_small, N);

    // layer 2
    k_gemm<<<dim3(mtiles, 4), 256, 0, stream>>>(h_small, W2, nullptr, h_big, N, 256, 64);
    k_attn_coef<<<nwb, 256, 0, stream>>>(h_big, asrc2, adst2, es, ed, N);
    k_gat_aggregate<<<nwb, 256, 0, stream>>>(h_big, es, ed, rowstart, colarr, b2, g2, be2, h_small, N);

    // output projection
    k_gemm<<<dim3(mtiles, 2), 256, 0, stream>>>(h_small, Wo, bo, (float*)d_out, N, 128, 64);
}

// Round 2
// 526.483 us; speedup vs baseline: 1.1550x; 1.1550x over previous
//
#include <hip/hip_runtime.h>

#define NHEADS 4
#define NEG_SLOPE 0.2f
#define EPS_LN 1e-5f

// ---------------- CSR build ----------------
__global__ __launch_bounds__(256) void k_init_deg(int* __restrict__ deg, int n) {
    int i = blockIdx.x * 256 + threadIdx.x;
    if (i < n) deg[i] = 1;  // self-loop
}

__global__ __launch_bounds__(256) void k_count(const int* __restrict__ dst, int* __restrict__ deg, int e) {
    int i = blockIdx.x * 256 + threadIdx.x;
    if (i < e) atomicAdd(&deg[dst[i]], 1);
}

__global__ __launch_bounds__(256) void k_scan1(const int* __restrict__ deg, int* __restrict__ rs,
                                               int* __restrict__ bsum, int n) {
    __shared__ int tmp[256];
    int tx = threadIdx.x;
    int i = blockIdx.x * 256 + tx;
    int v = (i < n) ? deg[i] : 0;
    tmp[tx] = v;
    __syncthreads();
    for (int off = 1; off < 256; off <<= 1) {
        int t = (tx >= off) ? tmp[tx - off] : 0;
        __syncthreads();
        tmp[tx] += t;
        __syncthreads();
    }
    if (i < n) rs[i] = tmp[tx] - v;
    if (tx == 255) bsum[blockIdx.x] = tmp[255];
}

__global__ __launch_bounds__(256) void k_scan2(int* __restrict__ bsum, int nb) {
    __shared__ int tmp[256];
    int tx = threadIdx.x;
    int v = (tx < nb) ? bsum[tx] : 0;
    tmp[tx] = v;
    __syncthreads();
    for (int off = 1; off < 256; off <<= 1) {
        int t = (tx >= off) ? tmp[tx - off] : 0;
        __syncthreads();
        tmp[tx] += t;
        __syncthreads();
    }
    if (tx < nb) bsum[tx] = tmp[tx] - v;
}

__global__ __launch_bounds__(256) void k_scan3(int* __restrict__ rs, int* __restrict__ cur,
                                               const int* __restrict__ bsum, int n, int total) {
    int i = blockIdx.x * 256 + threadIdx.x;
    if (i < n) {
        int r = rs[i] + bsum[blockIdx.x];
        rs[i] = r;
        cur[i] = r;
    }
    if (i == 0) rs[n] = total;
}

__global__ __launch_bounds__(256) void k_scatter(const int* __restrict__ src, const int* __restrict__ dst,
                                                 int* __restrict__ cur, int* __restrict__ col, int e, int n) {
    int i = blockIdx.x * 256 + threadIdx.x;
    if (i < e + n) {
        int s, d;
        if (i < e) { s = src[i]; d = dst[i]; }
        else       { s = i - e;  d = i - e;  }
        int p = atomicAdd(&cur[d], 1);
        col[p] = s;
    }
}

__device__ __forceinline__ unsigned pack_bf16(float a, float b) {
    unsigned ua = __float_as_uint(a); ua += 0x7fffu + ((ua >> 16) & 1u);
    unsigned ub = __float_as_uint(b); ub += 0x7fffu + ((ub >> 16) & 1u);
    return (ua >> 16) | (ub & 0xffff0000u);
}

// ---------------- GEMM (fp32 in) -> bf16 h + fused attention coefficients ----------------
// C = A[M,K] @ B[K,256]; N fixed at 256; blockIdx.y = head (64-col tile == one head).
// Writes Hb [M][4][64] bf16-packed and es/ed [M,4] fp32 (from fp32 accumulators).
__global__ __launch_bounds__(256) void k_gemm_gat(const float* __restrict__ A, const float* __restrict__ B,
                                                  const float* __restrict__ asrc, const float* __restrict__ adst,
                                                  unsigned* __restrict__ Hb, float* __restrict__ es,
                                                  float* __restrict__ ed, int M, int K) {
    __shared__ float As[16][68];
    __shared__ float Bs[16][68];
    int tid = threadIdx.x;
    int m0 = blockIdx.x * 64;
    int head = blockIdx.y;
    int n0 = head * 64;
    int ty = tid >> 4, tx = tid & 15;
    int lm = tid >> 2;
    int lk4 = (tid & 3) * 4;
    int lkb = tid >> 4;
    int lnb = (tid & 15) * 4;
    float acc[4][4] = {};
    for (int k0 = 0; k0 < K; k0 += 16) {
        float4 a4 = make_float4(0.f, 0.f, 0.f, 0.f);
        int am = m0 + lm;
        if (am < M) a4 = *(const float4*)&A[(size_t)am * K + k0 + lk4];
        As[lk4 + 0][lm] = a4.x; As[lk4 + 1][lm] = a4.y;
        As[lk4 + 2][lm] = a4.z; As[lk4 + 3][lm] = a4.w;
        *(float4*)&Bs[lkb][lnb] = *(const float4*)&B[(size_t)(k0 + lkb) * 256 + n0 + lnb];
        __syncthreads();
#pragma unroll
        for (int k = 0; k < 16; k++) {
            float4 a = *(const float4*)&As[k][ty * 4];
            float4 b = *(const float4*)&Bs[k][tx * 4];
            acc[0][0] += a.x * b.x; acc[0][1] += a.x * b.y; acc[0][2] += a.x * b.z; acc[0][3] += a.x * b.w;
            acc[1][0] += a.y * b.x; acc[1][1] += a.y * b.y; acc[1][2] += a.y * b.z; acc[1][3] += a.y * b.w;
            acc[2][0] += a.z * b.x; acc[2][1] += a.z * b.y; acc[2][2] += a.z * b.z; acc[2][3] += a.z * b.w;
            acc[3][0] += a.w * b.x; acc[3][1] += a.w * b.y; acc[3][2] += a.w * b.z; acc[3][3] += a.w * b.w;
        }
        __syncthreads();
    }
    // epilogue: bf16 h write + es/ed (fp32-exact) via 16-lane row-group reduce
    float4 av = *(const float4*)&asrc[head * 64 + tx * 4];
    float4 dv = *(const float4*)&adst[head * 64 + tx * 4];
#pragma unroll
    for (int i = 0; i < 4; i++) {
        int m = m0 + ty * 4 + i;
        float se = acc[i][0] * av.x + acc[i][1] * av.y + acc[i][2] * av.z + acc[i][3] * av.w;
        float sd = acc[i][0] * dv.x + acc[i][1] * dv.y + acc[i][2] * dv.z + acc[i][3] * dv.w;
#pragma unroll
        for (int off = 1; off < 16; off <<= 1) {
            se += __shfl_xor(se, off, 64);
            sd += __shfl_xor(sd, off, 64);
        }
        if (m < M) {
            uint2 p;
            p.x = pack_bf16(acc[i][0], acc[i][1]);
            p.y = pack_bf16(acc[i][2], acc[i][3]);
            *(uint2*)&Hb[(size_t)m * 128 + head * 32 + tx * 2] = p;
            if (tx == 0) { es[m * 4 + head] = se; ed[m * 4 + head] = sd; }
        }
    }
}

// ---------------- fp32 tiled GEMM with bias (output projection) ----------------
__global__ __launch_bounds__(256) void k_gemm(const float* __restrict__ A, const float* __restrict__ B,
                                              const float* __restrict__ bias, float* __restrict__ C,
                                              int M, int N, int K) {
    __shared__ float As[16][68];
    __shared__ float Bs[16][68];
    int tid = threadIdx.x;
    int m0 = blockIdx.x * 64, n0 = blockIdx.y * 64;
    int ty = tid >> 4, tx = tid & 15;
    int lm = tid >> 2;
    int lk4 = (tid & 3) * 4;
    int lkb = tid >> 4;
    int lnb = (tid & 15) * 4;
    float acc[4][4] = {};
    for (int k0 = 0; k0 < K; k0 += 16) {
        float4 a4 = make_float4(0.f, 0.f, 0.f, 0.f);
        int am = m0 + lm;
        if (am < M) a4 = *(const float4*)&A[(size_t)am * K + k0 + lk4];
        As[lk4 + 0][lm] = a4.x; As[lk4 + 1][lm] = a4.y;
        As[lk4 + 2][lm] = a4.z; As[lk4 + 3][lm] = a4.w;
        *(float4*)&Bs[lkb][lnb] = *(const float4*)&B[(size_t)(k0 + lkb) * N + n0 + lnb];
        __syncthreads();
#pragma unroll
        for (int k = 0; k < 16; k++) {
            float4 a = *(const float4*)&As[k][ty * 4];
            float4 b = *(const float4*)&Bs[k][tx * 4];
            acc[0][0] += a.x * b.x; acc[0][1] += a.x * b.y; acc[0][2] += a.x * b.z; acc[0][3] += a.x * b.w;
            acc[1][0] += a.y * b.x; acc[1][1] += a.y * b.y; acc[1][2] += a.y * b.z; acc[1][3] += a.y * b.w;
            acc[2][0] += a.z * b.x; acc[2][1] += a.z * b.y; acc[2][2] += a.z * b.z; acc[2][3] += a.z * b.w;
            acc[3][0] += a.w * b.x; acc[3][1] += a.w * b.y; acc[3][2] += a.w * b.z; acc[3][3] += a.w * b.w;
        }
        __syncthreads();
    }
#pragma unroll
    for (int i = 0; i < 4; i++) {
        int m = m0 + ty * 4 + i;
        if (m < M) {
            int nbase = n0 + tx * 4;
            float4 r;
            r.x = acc[i][0] + bias[nbase + 0];
            r.y = acc[i][1] + bias[nbase + 1];
            r.z = acc[i][2] + bias[nbase + 2];
            r.w = acc[i][3] + bias[nbase + 3];
            *(float4*)&C[(size_t)m * N + nbase] = r;
        }
    }
}

// ---------------- fused GAT aggregate (bf16 gather) + head-mean + bias + LN + ReLU ----------------
// one wave per destination node; lane = channel; bf16 h row = 128 dwords [4 heads][32 dwords]
__global__ __launch_bounds__(256) void k_gat_aggregate(const unsigned* __restrict__ Hb, const float* __restrict__ es,
                                                       const float* __restrict__ ed, const int* __restrict__ rs,
                                                       const int* __restrict__ col, const float* __restrict__ b,
                                                       const float* __restrict__ g, const float* __restrict__ be,
                                                       float* __restrict__ out, int n) {
    int node = blockIdx.x * 4 + (threadIdx.x >> 6);
    int lane = threadIdx.x & 63;
    if (node >= n) return;
    float4 edv = *(const float4*)&ed[node * 4];
    int sh = (lane & 1) ? 0 : 16;     // even channel -> low bf16, odd -> high
    int dwo = lane >> 1;              // dword within head block
    float acc0 = 0.f, acc1 = 0.f, acc2 = 0.f, acc3 = 0.f;
    float den0 = 0.f, den1 = 0.f, den2 = 0.f, den3 = 0.f;
    int i0 = rs[node], i1 = rs[node + 1];
    for (int i = i0; i < i1; i++) {
        int s = col[i];
        float4 esv = *(const float4*)&es[s * 4];
        float e0 = esv.x + edv.x, e1 = esv.y + edv.y, e2 = esv.z + edv.z, e3 = esv.w + edv.w;
        e0 = fmaxf(e0, NEG_SLOPE * e0);   // leaky relu
        e1 = fmaxf(e1, NEG_SLOPE * e1);
        e2 = fmaxf(e2, NEG_SLOPE * e2);
        e3 = fmaxf(e3, NEG_SLOPE * e3);
        float w0 = __expf(e0), w1 = __expf(e1), w2 = __expf(e2), w3 = __expf(e3);
        const unsigned* hp = Hb + (size_t)s * 128 + dwo;
        unsigned u0 = hp[0], u1 = hp[32], u2 = hp[64], u3 = hp[96];
        acc0 += w0 * __uint_as_float((u0 << sh) & 0xffff0000u);
        acc1 += w1 * __uint_as_float((u1 << sh) & 0xffff0000u);
        acc2 += w2 * __uint_as_float((u2 << sh) & 0xffff0000u);
        acc3 += w3 * __uint_as_float((u3 << sh) & 0xffff0000u);
        den0 += w0; den1 += w1; den2 += w2; den3 += w3;
    }
    float val = 0.25f * (acc0 / den0 + acc1 / den1 + acc2 / den2 + acc3 / den3) + b[lane];
    float s = val, q = val * val;
    for (int off = 32; off; off >>= 1) {
        s += __shfl_xor(s, off, 64);
        q += __shfl_xor(q, off, 64);
    }
    float mean = s * (1.f / 64.f);
    float var = q * (1.f / 64.f) - mean * mean;
    float y = (val - mean) * rsqrtf(var + EPS_LN) * g[lane] + be[lane];
    out[(size_t)node * 64 + lane] = fmaxf(y, 0.f);
}

// ---------------- launch ----------------
extern "C" void kernel_launch(void* const* d_in, const int* in_sizes, int n_in,
                              void* d_out, int out_size, void* d_ws, size_t ws_size,
                              hipStream_t stream) {
    const float* x     = (const float*)d_in[0];
    const int*   eidx  = (const int*)d_in[1];
    const float* W1    = (const float*)d_in[2];
    const float* asrc1 = (const float*)d_in[3];
    const float* adst1 = (const float*)d_in[4];
    const float* b1    = (const float*)d_in[5];
    const float* g1    = (const float*)d_in[6];
    const float* be1   = (const float*)d_in[7];
    const float* W2    = (const float*)d_in[8];
    const float* asrc2 = (const float*)d_in[9];
    const float* adst2 = (const float*)d_in[10];
    const float* b2    = (const float*)d_in[11];
    const float* g2    = (const float*)d_in[12];
    const float* be2   = (const float*)d_in[13];
    const float* Wo    = (const float*)d_in[14];
    const float* bo    = (const float*)d_in[15];

    const int N = in_sizes[0] / 128;
    const int E = in_sizes[1] / 2;
    const int* srcp = eidx;
    const int* dstp = eidx + E;

    // workspace layout
    unsigned* hb   = (unsigned*)d_ws;                       // [N*128] bf16x2 (h1, then h3)
    float* h_small = (float*)(hb + (size_t)N * 128);        // [N,64] fp32 (h2, then h4)
    float* es      = h_small + (size_t)N * 64;              // [N,4]
    float* ed      = es + (size_t)N * 4;                    // [N,4]
    int* deg       = (int*)(ed + (size_t)N * 4);            // [N]
    int* rowstart  = deg + N;                               // [N+1]
    int* cursor    = rowstart + (N + 1);                    // [N]
    int* colarr    = cursor + N;                            // [E+N]
    int* bsum      = colarr + (size_t)(E + N);              // [<=256]

    const int nb = (N + 255) / 256;
    const int nwb = (N + 3) / 4;
    const int mtiles = (N + 63) / 64;

    // CSR build
    k_init_deg<<<nb, 256, 0, stream>>>(deg, N);
    k_count<<<(E + 255) / 256, 256, 0, stream>>>(dstp, deg, E);
    k_scan1<<<nb, 256, 0, stream>>>(deg, rowstart, bsum, N);
    k_scan2<<<1, 256, 0, stream>>>(bsum, nb);
    k_scan3<<<nb, 256, 0, stream>>>(rowstart, cursor, bsum, N, E + N);
    k_scatter<<<(E + N + 255) / 256, 256, 0, stream>>>(srcp, dstp, cursor, colarr, E, N);

    // layer 1: GEMM + fused attn coef (blockIdx.y = head)
    k_gemm_gat<<<dim3(mtiles, 4), 256, 0, stream>>>(x, W1, asrc1, adst1, hb, es, ed, N, 128);
    k_gat_aggregate<<<nwb, 256, 0, stream>>>(hb, es, ed, rowstart, colarr, b1, g1, be1, h_small, N);

    // layer 2
    k_gemm_gat<<<dim3(mtiles, 4), 256, 0, stream>>>(h_small, W2, asrc2, adst2, hb, es, ed, N, 64);
    k_gat_aggregate<<<nwb, 256, 0, stream>>>(hb, es, ed, rowstart, colarr, b2, g2, be2, h_small, N);

    // output projection (fp32)
    k_gemm<<<dim3(mtiles, 2), 256, 0, stream>>>(h_small, Wo, bo, (float*)d_out, N, 128, 64);
}

// Round 3
// 457.824 us; speedup vs baseline: 1.3282x; 1.1500x over previous
//
#include <hip/hip_runtime.h>

#define NHEADS 4
#define NEG_SLOPE 0.2f
#define EPS_LN 1e-5f

// ---------------- CSR build ----------------
__global__ __launch_bounds__(256) void k_init_deg(int* __restrict__ deg, int n) {
    int i = blockIdx.x * 256 + threadIdx.x;
    if (i < n) deg[i] = 1;  // self-loop
}

__global__ __launch_bounds__(256) void k_count(const int* __restrict__ dst, int* __restrict__ deg, int e) {
    int i = blockIdx.x * 256 + threadIdx.x;
    if (i < e) atomicAdd(&deg[dst[i]], 1);
}

__global__ __launch_bounds__(256) void k_scan1(const int* __restrict__ deg, int* __restrict__ rs,
                                               int* __restrict__ bsum, int n) {
    __shared__ int tmp[256];
    int tx = threadIdx.x;
    int i = blockIdx.x * 256 + tx;
    int v = (i < n) ? deg[i] : 0;
    tmp[tx] = v;
    __syncthreads();
    for (int off = 1; off < 256; off <<= 1) {
        int t = (tx >= off) ? tmp[tx - off] : 0;
        __syncthreads();
        tmp[tx] += t;
        __syncthreads();
    }
    if (i < n) rs[i] = tmp[tx] - v;
    if (tx == 255) bsum[blockIdx.x] = tmp[255];
}

__global__ __launch_bounds__(256) void k_scan2(int* __restrict__ bsum, int nb) {
    __shared__ int tmp[256];
    int tx = threadIdx.x;
    int v = (tx < nb) ? bsum[tx] : 0;
    tmp[tx] = v;
    __syncthreads();
    for (int off = 1; off < 256; off <<= 1) {
        int t = (tx >= off) ? tmp[tx - off] : 0;
        __syncthreads();
        tmp[tx] += t;
        __syncthreads();
    }
    if (tx < nb) bsum[tx] = tmp[tx] - v;
}

__global__ __launch_bounds__(256) void k_scan3(int* __restrict__ rs, int* __restrict__ cur,
                                               const int* __restrict__ bsum, int n, int total) {
    int i = blockIdx.x * 256 + threadIdx.x;
    if (i < n) {
        int r = rs[i] + bsum[blockIdx.x];
        rs[i] = r;
        cur[i] = r;
    }
    if (i == 0) rs[n] = total;
}

__global__ __launch_bounds__(256) void k_scatter(const int* __restrict__ src, const int* __restrict__ dst,
                                                 int* __restrict__ cur, int* __restrict__ col, int e, int n) {
    int i = blockIdx.x * 256 + threadIdx.x;
    if (i < e + n) {
        int s, d;
        if (i < e) { s = src[i]; d = dst[i]; }
        else       { s = i - e;  d = i - e;  }
        int p = atomicAdd(&cur[d], 1);
        col[p] = s;
    }
}

__device__ __forceinline__ unsigned pack_bf16(float a, float b) {
    unsigned ua = __float_as_uint(a); ua += 0x7fffu + ((ua >> 16) & 1u);
    unsigned ub = __float_as_uint(b); ub += 0x7fffu + ((ub >> 16) & 1u);
    return (ua >> 16) | (ub & 0xffff0000u);
}

// ---------------- GEMM (fp32 in) -> bf16 h + fused attention coefficients ----------------
// C = A[M,K] @ B[K,256]; blockIdx.y = head (64-col tile == one head).
// Writes Hb [M][4][32] dwords (bf16 pairs) and es/ed [M,4] fp32 (from fp32 accumulators).
__global__ __launch_bounds__(256) void k_gemm_gat(const float* __restrict__ A, const float* __restrict__ B,
                                                  const float* __restrict__ asrc, const float* __restrict__ adst,
                                                  unsigned* __restrict__ Hb, float* __restrict__ es,
                                                  float* __restrict__ ed, int M, int K) {
    __shared__ float As[16][68];
    __shared__ float Bs[16][68];
    int tid = threadIdx.x;
    int m0 = blockIdx.x * 64;
    int head = blockIdx.y;
    int n0 = head * 64;
    int ty = tid >> 4, tx = tid & 15;
    int lm = tid >> 2;
    int lk4 = (tid & 3) * 4;
    int lkb = tid >> 4;
    int lnb = (tid & 15) * 4;
    float acc[4][4] = {};
    for (int k0 = 0; k0 < K; k0 += 16) {
        float4 a4 = make_float4(0.f, 0.f, 0.f, 0.f);
        int am = m0 + lm;
        if (am < M) a4 = *(const float4*)&A[(size_t)am * K + k0 + lk4];
        As[lk4 + 0][lm] = a4.x; As[lk4 + 1][lm] = a4.y;
        As[lk4 + 2][lm] = a4.z; As[lk4 + 3][lm] = a4.w;
        *(float4*)&Bs[lkb][lnb] = *(const float4*)&B[(size_t)(k0 + lkb) * 256 + n0 + lnb];
        __syncthreads();
#pragma unroll
        for (int k = 0; k < 16; k++) {
            float4 a = *(const float4*)&As[k][ty * 4];
            float4 b = *(const float4*)&Bs[k][tx * 4];
            acc[0][0] += a.x * b.x; acc[0][1] += a.x * b.y; acc[0][2] += a.x * b.z; acc[0][3] += a.x * b.w;
            acc[1][0] += a.y * b.x; acc[1][1] += a.y * b.y; acc[1][2] += a.y * b.z; acc[1][3] += a.y * b.w;
            acc[2][0] += a.z * b.x; acc[2][1] += a.z * b.y; acc[2][2] += a.z * b.z; acc[2][3] += a.z * b.w;
            acc[3][0] += a.w * b.x; acc[3][1] += a.w * b.y; acc[3][2] += a.w * b.z; acc[3][3] += a.w * b.w;
        }
        __syncthreads();
    }
    // epilogue: bf16 h write + es/ed (fp32-exact) via 16-lane row-group reduce
    float4 av = *(const float4*)&asrc[head * 64 + tx * 4];
    float4 dv = *(const float4*)&adst[head * 64 + tx * 4];
#pragma unroll
    for (int i = 0; i < 4; i++) {
        int m = m0 + ty * 4 + i;
        float se = acc[i][0] * av.x + acc[i][1] * av.y + acc[i][2] * av.z + acc[i][3] * av.w;
        float sd = acc[i][0] * dv.x + acc[i][1] * dv.y + acc[i][2] * dv.z + acc[i][3] * dv.w;
#pragma unroll
        for (int off = 1; off < 16; off <<= 1) {
            se += __shfl_xor(se, off, 64);
            sd += __shfl_xor(sd, off, 64);
        }
        if (m < M) {
            uint2 p;
            p.x = pack_bf16(acc[i][0], acc[i][1]);
            p.y = pack_bf16(acc[i][2], acc[i][3]);
            *(uint2*)&Hb[(size_t)m * 128 + head * 32 + tx * 2] = p;
            if (tx == 0) { es[m * 4 + head] = se; ed[m * 4 + head] = sd; }
        }
    }
}

// ---------------- fp32 tiled GEMM with bias (output projection) ----------------
__global__ __launch_bounds__(256) void k_gemm(const float* __restrict__ A, const float* __restrict__ B,
                                              const float* __restrict__ bias, float* __restrict__ C,
                                              int M, int N, int K) {
    __shared__ float As[16][68];
    __shared__ float Bs[16][68];
    int tid = threadIdx.x;
    int m0 = blockIdx.x * 64, n0 = blockIdx.y * 64;
    int ty = tid >> 4, tx = tid & 15;
    int lm = tid >> 2;
    int lk4 = (tid & 3) * 4;
    int lkb = tid >> 4;
    int lnb = (tid & 15) * 4;
    float acc[4][4] = {};
    for (int k0 = 0; k0 < K; k0 += 16) {
        float4 a4 = make_float4(0.f, 0.f, 0.f, 0.f);
        int am = m0 + lm;
        if (am < M) a4 = *(const float4*)&A[(size_t)am * K + k0 + lk4];
        As[lk4 + 0][lm] = a4.x; As[lk4 + 1][lm] = a4.y;
        As[lk4 + 2][lm] = a4.z; As[lk4 + 3][lm] = a4.w;
        *(float4*)&Bs[lkb][lnb] = *(const float4*)&B[(size_t)(k0 + lkb) * N + n0 + lnb];
        __syncthreads();
#pragma unroll
        for (int k = 0; k < 16; k++) {
            float4 a = *(const float4*)&As[k][ty * 4];
            float4 b = *(const float4*)&Bs[k][tx * 4];
            acc[0][0] += a.x * b.x; acc[0][1] += a.x * b.y; acc[0][2] += a.x * b.z; acc[0][3] += a.x * b.w;
            acc[1][0] += a.y * b.x; acc[1][1] += a.y * b.y; acc[1][2] += a.y * b.z; acc[1][3] += a.y * b.w;
            acc[2][0] += a.z * b.x; acc[2][1] += a.z * b.y; acc[2][2] += a.z * b.z; acc[2][3] += a.z * b.w;
            acc[3][0] += a.w * b.x; acc[3][1] += a.w * b.y; acc[3][2] += a.w * b.z; acc[3][3] += a.w * b.w;
        }
        __syncthreads();
    }
#pragma unroll
    for (int i = 0; i < 4; i++) {
        int m = m0 + ty * 4 + i;
        if (m < M) {
            int nbase = n0 + tx * 4;
            float4 r;
            r.x = acc[i][0] + bias[nbase + 0];
            r.y = acc[i][1] + bias[nbase + 1];
            r.z = acc[i][2] + bias[nbase + 2];
            r.w = acc[i][3] + bias[nbase + 3];
            *(float4*)&C[(size_t)m * N + nbase] = r;
        }
    }
}

// ---------------- fused GAT aggregate (bf16 gather) + head-mean + bias + LN + ReLU ----------------
// one wave per destination node. lane = (head, channel-quad): head = lane>>4,
// channels 4*(lane&15)..+3 of that head. One uint2 load per lane = full 512B row
// per wave in a single coalesced instruction; each lane computes only its own
// head's attention scalar (no 4x redundancy). Unroll-by-2 for gather MLP.
__global__ __launch_bounds__(256) void k_gat_aggregate(const unsigned* __restrict__ Hb, const float* __restrict__ es,
                                                       const float* __restrict__ ed, const int* __restrict__ rs,
                                                       const int* __restrict__ col, const float* __restrict__ b,
                                                       const float* __restrict__ g, const float* __restrict__ be,
                                                       float* __restrict__ out, int n) {
    int node = blockIdx.x * 4 + (threadIdx.x >> 6);
    int lane = threadIdx.x & 63;
    if (node >= n) return;
    int head = lane >> 4;
    int cp = lane & 15;
    float edv = ed[node * 4 + head];
    float acc0 = 0.f, acc1 = 0.f, acc2 = 0.f, acc3 = 0.f, den = 0.f;
    int i0 = rs[node], i1 = rs[node + 1];
    int i = i0;
    for (; i + 1 < i1; i += 2) {
        int s0 = col[i], s1 = col[i + 1];
        float e0 = es[s0 * 4 + head] + edv;
        float e1 = es[s1 * 4 + head] + edv;
        uint2 u0 = *(const uint2*)&Hb[(size_t)s0 * 128 + lane * 2];
        uint2 u1 = *(const uint2*)&Hb[(size_t)s1 * 128 + lane * 2];
        e0 = fmaxf(e0, NEG_SLOPE * e0);
        e1 = fmaxf(e1, NEG_SLOPE * e1);
        float w0 = __expf(e0), w1 = __expf(e1);
        acc0 += w0 * __uint_as_float(u0.x << 16);
        acc1 += w0 * __uint_as_float(u0.x & 0xffff0000u);
        acc2 += w0 * __uint_as_float(u0.y << 16);
        acc3 += w0 * __uint_as_float(u0.y & 0xffff0000u);
        den += w0;
        acc0 += w1 * __uint_as_float(u1.x << 16);
        acc1 += w1 * __uint_as_float(u1.x & 0xffff0000u);
        acc2 += w1 * __uint_as_float(u1.y << 16);
        acc3 += w1 * __uint_as_float(u1.y & 0xffff0000u);
        den += w1;
    }
    if (i < i1) {
        int s0 = col[i];
        float e0 = es[s0 * 4 + head] + edv;
        uint2 u0 = *(const uint2*)&Hb[(size_t)s0 * 128 + lane * 2];
        e0 = fmaxf(e0, NEG_SLOPE * e0);
        float w0 = __expf(e0);
        acc0 += w0 * __uint_as_float(u0.x << 16);
        acc1 += w0 * __uint_as_float(u0.x & 0xffff0000u);
        acc2 += w0 * __uint_as_float(u0.y << 16);
        acc3 += w0 * __uint_as_float(u0.y & 0xffff0000u);
        den += w0;
    }
    // softmax-normalize own head, then mean over heads via xor-16/32 butterflies
    float rd = 1.f / den;
    float r0 = acc0 * rd, r1 = acc1 * rd, r2 = acc2 * rd, r3 = acc3 * rd;
    r0 += __shfl_xor(r0, 16, 64); r1 += __shfl_xor(r1, 16, 64);
    r2 += __shfl_xor(r2, 16, 64); r3 += __shfl_xor(r3, 16, 64);
    r0 += __shfl_xor(r0, 32, 64); r1 += __shfl_xor(r1, 32, 64);
    r2 += __shfl_xor(r2, 32, 64); r3 += __shfl_xor(r3, 32, 64);
    float4 bb = *(const float4*)&b[cp * 4];
    float v0 = 0.25f * r0 + bb.x;
    float v1 = 0.25f * r1 + bb.y;
    float v2 = 0.25f * r2 + bb.z;
    float v3 = 0.25f * r3 + bb.w;
    // LayerNorm over 64 channels: reduce within the 16-lane head group (groups identical)
    float s = v0 + v1 + v2 + v3;
    float q = v0 * v0 + v1 * v1 + v2 * v2 + v3 * v3;
    for (int off = 1; off < 16; off <<= 1) {
        s += __shfl_xor(s, off, 64);
        q += __shfl_xor(q, off, 64);
    }
    float mean = s * (1.f / 64.f);
    float var = q * (1.f / 64.f) - mean * mean;
    float rinv = rsqrtf(var + EPS_LN);
    float4 gg = *(const float4*)&g[cp * 4];
    float4 ee = *(const float4*)&be[cp * 4];
    if (head == 0) {
        float4 y;
        y.x = fmaxf((v0 - mean) * rinv * gg.x + ee.x, 0.f);
        y.y = fmaxf((v1 - mean) * rinv * gg.y + ee.y, 0.f);
        y.z = fmaxf((v2 - mean) * rinv * gg.z + ee.z, 0.f);
        y.w = fmaxf((v3 - mean) * rinv * gg.w + ee.w, 0.f);
        *(float4*)&out[(size_t)node * 64 + cp * 4] = y;
    }
}

// ---------------- launch ----------------
extern "C" void kernel_launch(void* const* d_in, const int* in_sizes, int n_in,
                              void* d_out, int out_size, void* d_ws, size_t ws_size,
                              hipStream_t stream) {
    const float* x     = (const float*)d_in[0];
    const int*   eidx  = (const int*)d_in[1];
    const float* W1    = (const float*)d_in[2];
    const float* asrc1 = (const float*)d_in[3];
    const float* adst1 = (const float*)d_in[4];
    const float* b1    = (const float*)d_in[5];
    const float* g1    = (const float*)d_in[6];
    const float* be1   = (const float*)d_in[7];
    const float* W2    = (const float*)d_in[8];
    const float* asrc2 = (const float*)d_in[9];
    const float* adst2 = (const float*)d_in[10];
    const float* b2    = (const float*)d_in[11];
    const float* g2    = (const float*)d_in[12];
    const float* be2   = (const float*)d_in[13];
    const float* Wo    = (const float*)d_in[14];
    const float* bo    = (const float*)d_in[15];

    const int N = in_sizes[0] / 128;
    const int E = in_sizes[1] / 2;
    const int* srcp = eidx;
    const int* dstp = eidx + E;

    // workspace layout
    unsigned* hb   = (unsigned*)d_ws;                       // [N*128] bf16x2 (h1, then h3)
    float* h_small = (float*)(hb + (size_t)N * 128);        // [N,64] fp32 (h2, then h4)
    float* es      = h_small + (size_t)N * 64;              // [N,4]
    float* ed      = es + (size_t)N * 4;                    // [N,4]
    int* deg       = (int*)(ed + (size_t)N * 4);            // [N]
    int* rowstart  = deg + N;                               // [N+1]
    int* cursor    = rowstart + (N + 1);                    // [N]
    int* colarr    = cursor + N;                            // [E+N]
    int* bsum      = colarr + (size_t)(E + N);              // [<=256]

    const int nb = (N + 255) / 256;
    const int nwb = (N + 3) / 4;
    const int mtiles = (N + 63) / 64;

    // CSR build
    k_init_deg<<<nb, 256, 0, stream>>>(deg, N);
    k_count<<<(E + 255) / 256, 256, 0, stream>>>(dstp, deg, E);
    k_scan1<<<nb, 256, 0, stream>>>(deg, rowstart, bsum, N);
    k_scan2<<<1, 256, 0, stream>>>(bsum, nb);
    k_scan3<<<nb, 256, 0, stream>>>(rowstart, cursor, bsum, N, E + N);
    k_scatter<<<(E + N + 255) / 256, 256, 0, stream>>>(srcp, dstp, cursor, colarr, E, N);

    // layer 1: GEMM + fused attn coef (blockIdx.y = head)
    k_gemm_gat<<<dim3(mtiles, 4), 256, 0, stream>>>(x, W1, asrc1, adst1, hb, es, ed, N, 128);
    k_gat_aggregate<<<nwb, 256, 0, stream>>>(hb, es, ed, rowstart, colarr, b1, g1, be1, h_small, N);

    // layer 2
    k_gemm_gat<<<dim3(mtiles, 4), 256, 0, stream>>>(h_small, W2, asrc2, adst2, hb, es, ed, N, 64);
    k_gat_aggregate<<<nwb, 256, 0, stream>>>(hb, es, ed, rowstart, colarr, b2, g2, be2, h_small, N);

    // output projection (fp32)
    k_gemm<<<dim3(mtiles, 2), 256, 0, stream>>>(h_small, Wo, bo, (float*)d_out, N, 128, 64);
}

// Round 5
// 437.208 us; speedup vs baseline: 1.3909x; 1.0472x over previous
//
#include <hip/hip_runtime.h>

#define NHEADS 4
#define NEG_SLOPE 0.2f
#define EPS_LN 1e-5f

// ---------------- CSR build ----------------
__global__ __launch_bounds__(256) void k_init_deg(int* __restrict__ deg, int n) {
    int i = blockIdx.x * 256 + threadIdx.x;
    if (i < n) deg[i] = 1;  // self-loop
}

__global__ __launch_bounds__(256) void k_count(const int* __restrict__ dst, int* __restrict__ deg, int e) {
    int i = blockIdx.x * 256 + threadIdx.x;
    if (i < e) atomicAdd(&deg[dst[i]], 1);
}

__global__ __launch_bounds__(256) void k_scan1(const int* __restrict__ deg, int* __restrict__ rs,
                                               int* __restrict__ bsum, int n) {
    __shared__ int tmp[256];
    int tx = threadIdx.x;
    int i = blockIdx.x * 256 + tx;
    int v = (i < n) ? deg[i] : 0;
    tmp[tx] = v;
    __syncthreads();
    for (int off = 1; off < 256; off <<= 1) {
        int t = (tx >= off) ? tmp[tx - off] : 0;
        __syncthreads();
        tmp[tx] += t;
        __syncthreads();
    }
    if (i < n) rs[i] = tmp[tx] - v;
    if (tx == 255) bsum[blockIdx.x] = tmp[255];
}

__global__ __launch_bounds__(256) void k_scan2(int* __restrict__ bsum, int nb) {
    __shared__ int tmp[256];
    int tx = threadIdx.x;
    int v = (tx < nb) ? bsum[tx] : 0;
    tmp[tx] = v;
    __syncthreads();
    for (int off = 1; off < 256; off <<= 1) {
        int t = (tx >= off) ? tmp[tx - off] : 0;
        __syncthreads();
        tmp[tx] += t;
        __syncthreads();
    }
    if (tx < nb) bsum[tx] = tmp[tx] - v;
}

__global__ __launch_bounds__(256) void k_scan3(int* __restrict__ rs, int* __restrict__ cur,
                                               const int* __restrict__ bsum, int n, int total) {
    int i = blockIdx.x * 256 + threadIdx.x;
    if (i < n) {
        int r = rs[i] + bsum[blockIdx.x];
        rs[i] = r;
        cur[i] = r;
    }
    if (i == 0) rs[n] = total;
}

__global__ __launch_bounds__(256) void k_scatter(const int* __restrict__ src, const int* __restrict__ dst,
                                                 int* __restrict__ cur, int* __restrict__ col, int e, int n) {
    int i = blockIdx.x * 256 + threadIdx.x;
    if (i < e + n) {
        int s, d;
        if (i < e) { s = src[i]; d = dst[i]; }
        else       { s = i - e;  d = i - e;  }
        int p = atomicAdd(&cur[d], 1);
        col[p] = s;
    }
}

__device__ __forceinline__ unsigned pack_bf16(float a, float b) {
    unsigned ua = __float_as_uint(a); ua += 0x7fffu + ((ua >> 16) & 1u);
    unsigned ub = __float_as_uint(b); ub += 0x7fffu + ((ub >> 16) & 1u);
    return (ua >> 16) | (ub & 0xffff0000u);
}

// ---------------- GEMM (fp32 in) -> bf16 h + fused attention coefficients ----------------
// C = A[M,K] @ B[K,256]; blockIdx.y = head (64-col tile == one head).
// (Round-3 proven version; the 4-head-wide variant caused replay divergence in R4.)
__global__ __launch_bounds__(256) void k_gemm_gat(const float* __restrict__ A, const float* __restrict__ B,
                                                  const float* __restrict__ asrc, const float* __restrict__ adst,
                                                  unsigned* __restrict__ Hb, float* __restrict__ es,
                                                  float* __restrict__ ed, int M, int K) {
    __shared__ float As[16][68];
    __shared__ float Bs[16][68];
    int tid = threadIdx.x;
    int m0 = blockIdx.x * 64;
    int head = blockIdx.y;
    int n0 = head * 64;
    int ty = tid >> 4, tx = tid & 15;
    int lm = tid >> 2;
    int lk4 = (tid & 3) * 4;
    int lkb = tid >> 4;
    int lnb = (tid & 15) * 4;
    float acc[4][4] = {};
    for (int k0 = 0; k0 < K; k0 += 16) {
        float4 a4 = make_float4(0.f, 0.f, 0.f, 0.f);
        int am = m0 + lm;
        if (am < M) a4 = *(const float4*)&A[(size_t)am * K + k0 + lk4];
        As[lk4 + 0][lm] = a4.x; As[lk4 + 1][lm] = a4.y;
        As[lk4 + 2][lm] = a4.z; As[lk4 + 3][lm] = a4.w;
        *(float4*)&Bs[lkb][lnb] = *(const float4*)&B[(size_t)(k0 + lkb) * 256 + n0 + lnb];
        __syncthreads();
#pragma unroll
        for (int k = 0; k < 16; k++) {
            float4 a = *(const float4*)&As[k][ty * 4];
            float4 b = *(const float4*)&Bs[k][tx * 4];
            acc[0][0] += a.x * b.x; acc[0][1] += a.x * b.y; acc[0][2] += a.x * b.z; acc[0][3] += a.x * b.w;
            acc[1][0] += a.y * b.x; acc[1][1] += a.y * b.y; acc[1][2] += a.y * b.z; acc[1][3] += a.y * b.w;
            acc[2][0] += a.z * b.x; acc[2][1] += a.z * b.y; acc[2][2] += a.z * b.z; acc[2][3] += a.z * b.w;
            acc[3][0] += a.w * b.x; acc[3][1] += a.w * b.y; acc[3][2] += a.w * b.z; acc[3][3] += a.w * b.w;
        }
        __syncthreads();
    }
    // epilogue: bf16 h write + es/ed (fp32-exact) via 16-lane row-group reduce
    float4 av = *(const float4*)&asrc[head * 64 + tx * 4];
    float4 dv = *(const float4*)&adst[head * 64 + tx * 4];
#pragma unroll
    for (int i = 0; i < 4; i++) {
        int m = m0 + ty * 4 + i;
        float se = acc[i][0] * av.x + acc[i][1] * av.y + acc[i][2] * av.z + acc[i][3] * av.w;
        float sd = acc[i][0] * dv.x + acc[i][1] * dv.y + acc[i][2] * dv.z + acc[i][3] * dv.w;
#pragma unroll
        for (int off = 1; off < 16; off <<= 1) {
            se += __shfl_xor(se, off, 64);
            sd += __shfl_xor(sd, off, 64);
        }
        if (m < M) {
            uint2 p;
            p.x = pack_bf16(acc[i][0], acc[i][1]);
            p.y = pack_bf16(acc[i][2], acc[i][3]);
            *(uint2*)&Hb[(size_t)m * 128 + head * 32 + tx * 2] = p;
            if (tx == 0) { es[m * 4 + head] = se; ed[m * 4 + head] = sd; }
        }
    }
}

// ---------------- fp32 tiled GEMM with bias (output projection) ----------------
__global__ __launch_bounds__(256) void k_gemm(const float* __restrict__ A, const float* __restrict__ B,
                                              const float* __restrict__ bias, float* __restrict__ C,
                                              int M, int N, int K) {
    __shared__ float As[16][68];
    __shared__ float Bs[16][68];
    int tid = threadIdx.x;
    int m0 = blockIdx.x * 64, n0 = blockIdx.y * 64;
    int ty = tid >> 4, tx = tid & 15;
    int lm = tid >> 2;
    int lk4 = (tid & 3) * 4;
    int lkb = tid >> 4;
    int lnb = (tid & 15) * 4;
    float acc[4][4] = {};
    for (int k0 = 0; k0 < K; k0 += 16) {
        float4 a4 = make_float4(0.f, 0.f, 0.f, 0.f);
        int am = m0 + lm;
        if (am < M) a4 = *(const float4*)&A[(size_t)am * K + k0 + lk4];
        As[lk4 + 0][lm] = a4.x; As[lk4 + 1][lm] = a4.y;
        As[lk4 + 2][lm] = a4.z; As[lk4 + 3][lm] = a4.w;
        *(float4*)&Bs[lkb][lnb] = *(const float4*)&B[(size_t)(k0 + lkb) * N + n0 + lnb];
        __syncthreads();
#pragma unroll
        for (int k = 0; k < 16; k++) {
            float4 a = *(const float4*)&As[k][ty * 4];
            float4 b = *(const float4*)&Bs[k][tx * 4];
            acc[0][0] += a.x * b.x; acc[0][1] += a.x * b.y; acc[0][2] += a.x * b.z; acc[0][3] += a.x * b.w;
            acc[1][0] += a.y * b.x; acc[1][1] += a.y * b.y; acc[1][2] += a.y * b.z; acc[1][3] += a.y * b.w;
            acc[2][0] += a.z * b.x; acc[2][1] += a.z * b.y; acc[2][2] += a.z * b.z; acc[2][3] += a.z * b.w;
            acc[3][0] += a.w * b.x; acc[3][1] += a.w * b.y; acc[3][2] += a.w * b.z; acc[3][3] += a.w * b.w;
        }
        __syncthreads();
    }
#pragma unroll
    for (int i = 0; i < 4; i++) {
        int m = m0 + ty * 4 + i;
        if (m < M) {
            int nbase = n0 + tx * 4;
            float4 r;
            r.x = acc[i][0] + bias[nbase + 0];
            r.y = acc[i][1] + bias[nbase + 1];
            r.z = acc[i][2] + bias[nbase + 2];
            r.w = acc[i][3] + bias[nbase + 3];
            *(float4*)&C[(size_t)m * N + nbase] = r;
        }
    }
}

// ---------------- fused GAT aggregate (bf16 gather) + head-mean + bias + LN + ReLU ----------------
// one wave per destination node; lane = (head, channel-quad). Unroll-4 with hoisted
// loads: 4 independent col->(es,Hb) chains in flight per wave for gather MLP.
__global__ __launch_bounds__(256) void k_gat_aggregate(const unsigned* __restrict__ Hb, const float* __restrict__ es,
                                                       const float* __restrict__ ed, const int* __restrict__ rs,
                                                       const int* __restrict__ col, const float* __restrict__ b,
                                                       const float* __restrict__ g, const float* __restrict__ be,
                                                       float* __restrict__ out, int n) {
    int node = blockIdx.x * 4 + (threadIdx.x >> 6);
    int lane = threadIdx.x & 63;
    if (node >= n) return;
    int head = lane >> 4;
    int cp = lane & 15;
    float edv = ed[node * 4 + head];
    float acc0 = 0.f, acc1 = 0.f, acc2 = 0.f, acc3 = 0.f, den = 0.f;
    int i0 = rs[node], i1 = rs[node + 1];
    int i = i0;
    for (; i + 3 < i1; i += 4) {
        int s0 = col[i], s1 = col[i + 1], s2 = col[i + 2], s3 = col[i + 3];
        float e0 = es[s0 * 4 + head];
        float e1 = es[s1 * 4 + head];
        float e2 = es[s2 * 4 + head];
        float e3 = es[s3 * 4 + head];
        uint2 u0 = *(const uint2*)&Hb[(size_t)s0 * 128 + lane * 2];
        uint2 u1 = *(const uint2*)&Hb[(size_t)s1 * 128 + lane * 2];
        uint2 u2 = *(const uint2*)&Hb[(size_t)s2 * 128 + lane * 2];
        uint2 u3 = *(const uint2*)&Hb[(size_t)s3 * 128 + lane * 2];
        e0 += edv; e1 += edv; e2 += edv; e3 += edv;
        e0 = fmaxf(e0, NEG_SLOPE * e0);
        e1 = fmaxf(e1, NEG_SLOPE * e1);
        e2 = fmaxf(e2, NEG_SLOPE * e2);
        e3 = fmaxf(e3, NEG_SLOPE * e3);
        float w0 = __expf(e0), w1 = __expf(e1), w2 = __expf(e2), w3 = __expf(e3);
        acc0 += w0 * __uint_as_float(u0.x << 16);
        acc1 += w0 * __uint_as_float(u0.x & 0xffff0000u);
        acc2 += w0 * __uint_as_float(u0.y << 16);
        acc3 += w0 * __uint_as_float(u0.y & 0xffff0000u);
        acc0 += w1 * __uint_as_float(u1.x << 16);
        acc1 += w1 * __uint_as_float(u1.x & 0xffff0000u);
        acc2 += w1 * __uint_as_float(u1.y << 16);
        acc3 += w1 * __uint_as_float(u1.y & 0xffff0000u);
        acc0 += w2 * __uint_as_float(u2.x << 16);
        acc1 += w2 * __uint_as_float(u2.x & 0xffff0000u);
        acc2 += w2 * __uint_as_float(u2.y << 16);
        acc3 += w2 * __uint_as_float(u2.y & 0xffff0000u);
        acc0 += w3 * __uint_as_float(u3.x << 16);
        acc1 += w3 * __uint_as_float(u3.x & 0xffff0000u);
        acc2 += w3 * __uint_as_float(u3.y << 16);
        acc3 += w3 * __uint_as_float(u3.y & 0xffff0000u);
        den += w0 + w1 + w2 + w3;
    }
    for (; i < i1; i++) {
        int s0 = col[i];
        float e0 = es[s0 * 4 + head] + edv;
        uint2 u0 = *(const uint2*)&Hb[(size_t)s0 * 128 + lane * 2];
        e0 = fmaxf(e0, NEG_SLOPE * e0);
        float w0 = __expf(e0);
        acc0 += w0 * __uint_as_float(u0.x << 16);
        acc1 += w0 * __uint_as_float(u0.x & 0xffff0000u);
        acc2 += w0 * __uint_as_float(u0.y << 16);
        acc3 += w0 * __uint_as_float(u0.y & 0xffff0000u);
        den += w0;
    }
    // softmax-normalize own head, then mean over heads via xor-16/32 butterflies
    float rd = 1.f / den;
    float r0 = acc0 * rd, r1 = acc1 * rd, r2 = acc2 * rd, r3 = acc3 * rd;
    r0 += __shfl_xor(r0, 16, 64); r1 += __shfl_xor(r1, 16, 64);
    r2 += __shfl_xor(r2, 16, 64); r3 += __shfl_xor(r3, 16, 64);
    r0 += __shfl_xor(r0, 32, 64); r1 += __shfl_xor(r1, 32, 64);
    r2 += __shfl_xor(r2, 32, 64); r3 += __shfl_xor(r3, 32, 64);
    float4 bb = *(const float4*)&b[cp * 4];
    float v0 = 0.25f * r0 + bb.x;
    float v1 = 0.25f * r1 + bb.y;
    float v2 = 0.25f * r2 + bb.z;
    float v3 = 0.25f * r3 + bb.w;
    // LayerNorm over 64 channels: reduce within the 16-lane head group (groups identical)
    float s = v0 + v1 + v2 + v3;
    float q = v0 * v0 + v1 * v1 + v2 * v2 + v3 * v3;
    for (int off = 1; off < 16; off <<= 1) {
        s += __shfl_xor(s, off, 64);
        q += __shfl_xor(q, off, 64);
    }
    float mean = s * (1.f / 64.f);
    float var = q * (1.f / 64.f) - mean * mean;
    float rinv = rsqrtf(var + EPS_LN);
    float4 gg = *(const float4*)&g[cp * 4];
    float4 ee = *(const float4*)&be[cp * 4];
    if (head == 0) {
        float4 y;
        y.x = fmaxf((v0 - mean) * rinv * gg.x + ee.x, 0.f);
        y.y = fmaxf((v1 - mean) * rinv * gg.y + ee.y, 0.f);
        y.z = fmaxf((v2 - mean) * rinv * gg.z + ee.z, 0.f);
        y.w = fmaxf((v3 - mean) * rinv * gg.w + ee.w, 0.f);
        *(float4*)&out[(size_t)node * 64 + cp * 4] = y;
    }
}

// ---------------- launch ----------------
extern "C" void kernel_launch(void* const* d_in, const int* in_sizes, int n_in,
                              void* d_out, int out_size, void* d_ws, size_t ws_size,
                              hipStream_t stream) {
    const float* x     = (const float*)d_in[0];
    const int*   eidx  = (const int*)d_in[1];
    const float* W1    = (const float*)d_in[2];
    const float* asrc1 = (const float*)d_in[3];
    const float* adst1 = (const float*)d_in[4];
    const float* b1    = (const float*)d_in[5];
    const float* g1    = (const float*)d_in[6];
    const float* be1   = (const float*)d_in[7];
    const float* W2    = (const float*)d_in[8];
    const float* asrc2 = (const float*)d_in[9];
    const float* adst2 = (const float*)d_in[10];
    const float* b2    = (const float*)d_in[11];
    const float* g2    = (const float*)d_in[12];
    const float* be2   = (const float*)d_in[13];
    const float* Wo    = (const float*)d_in[14];
    const float* bo    = (const float*)d_in[15];

    const int N = in_sizes[0] / 128;
    const int E = in_sizes[1] / 2;
    const int* srcp = eidx;
    const int* dstp = eidx + E;

    // workspace layout
    unsigned* hb   = (unsigned*)d_ws;                       // [N*128] bf16x2 (h1, then h3)
    float* h_small = (float*)(hb + (size_t)N * 128);        // [N,64] fp32 (h2, then h4)
    float* es      = h_small + (size_t)N * 64;              // [N,4]
    float* ed      = es + (size_t)N * 4;                    // [N,4]
    int* deg       = (int*)(ed + (size_t)N * 4);            // [N]
    int* rowstart  = deg + N;                               // [N+1]
    int* cursor    = rowstart + (N + 1);                    // [N]
    int* colarr    = cursor + N;                            // [E+N]
    int* bsum      = colarr + (size_t)(E + N);              // [<=256]

    const int nb = (N + 255) / 256;
    const int nwb = (N + 3) / 4;
    const int mtiles = (N + 63) / 64;

    // CSR build
    k_init_deg<<<nb, 256, 0, stream>>>(deg, N);
    k_count<<<(E + 255) / 256, 256, 0, stream>>>(dstp, deg, E);
    k_scan1<<<nb, 256, 0, stream>>>(deg, rowstart, bsum, N);
    k_scan2<<<1, 256, 0, stream>>>(bsum, nb);
    k_scan3<<<nb, 256, 0, stream>>>(rowstart, cursor, bsum, N, E + N);
    k_scatter<<<(E + N + 255) / 256, 256, 0, stream>>>(srcp, dstp, cursor, colarr, E, N);

    // layer 1: GEMM + fused attn coef (blockIdx.y = head)
    k_gemm_gat<<<dim3(mtiles, 4), 256, 0, stream>>>(x, W1, asrc1, adst1, hb, es, ed, N, 128);
    k_gat_aggregate<<<nwb, 256, 0, stream>>>(hb, es, ed, rowstart, colarr, b1, g1, be1, h_small, N);

    // layer 2
    k_gemm_gat<<<dim3(mtiles, 4), 256, 0, stream>>>(h_small, W2, asrc2, adst2, hb, es, ed, N, 64);
    k_gat_aggregate<<<nwb, 256, 0, stream>>>(hb, es, ed, rowstart, colarr, b2, g2, be2, h_small, N);

    // output projection (fp32)
    k_gemm<<<dim3(mtiles, 2), 256, 0, stream>>>(h_small, Wo, bo, (float*)d_out, N, 128, 64);
}